// Round 1
// baseline (344.106 us; speedup 1.0000x reference)
//
#include <hip/hip_runtime.h>

#define NB      2
#define N_Q     20000
#define M_V     6890
#define N_F     13776
#define NCHUNK  8
#define CHUNK   1722        // 13776 / 8 exactly
#define RAD2    0.01f       // 0.1^2
#define THRESH  0.001f
#define EPSN    1e-7f
#define SCALE   (1.0f / (float)(NB * N_Q))

// ---------------- Kernel 1: per-face precompute ----------------
// face centroid (t1), prev centroid (t0 = cols 6..8), unit normal (t1)
__global__ __launch_bounds__(256) void face_kernel(
    const float* __restrict__ h_state,   // [NB][M_V][9]
    const int*   __restrict__ h_faces,   // [NB][N_F][3]
    float4* __restrict__ prev4,          // [NB*N_F]
    float4* __restrict__ pos4,           // [NB*N_F]
    float4* __restrict__ nrm4)           // [NB*N_F]
{
    int t = blockIdx.x * 256 + threadIdx.x;
    if (t >= NB * N_F) return;
    int b = t / N_F;
    const int* fc = h_faces + (size_t)t * 3;
    int i0 = fc[0], i1 = fc[1], i2 = fc[2];
    const float* hs = h_state + (size_t)b * M_V * 9;

    const float* v0 = hs + (size_t)i0 * 9;
    const float* v1 = hs + (size_t)i1 * 9;
    const float* v2 = hs + (size_t)i2 * 9;

    // t1 positions (cols 0..2)
    float ax = v0[0], ay = v0[1], az = v0[2];
    float bx = v1[0], by = v1[1], bz = v1[2];
    float cx = v2[0], cy = v2[1], cz = v2[2];

    float px = (ax + bx + cx) / 3.0f;
    float py = (ay + by + cy) / 3.0f;
    float pz = (az + bz + cz) / 3.0f;

    float e1x = bx - ax, e1y = by - ay, e1z = bz - az;
    float e2x = cx - ax, e2y = cy - ay, e2z = cz - az;
    float nx = e1y * e2z - e1z * e2y;
    float ny = e1z * e2x - e1x * e2z;
    float nz = e1x * e2y - e1y * e2x;
    float nrm = sqrtf(nx * nx + ny * ny + nz * nz);
    float den = fmaxf(nrm, EPSN);
    nx = nx / den; ny = ny / den; nz = nz / den;

    // t0 positions (cols 6..8)
    float qx = (v0[6] + v1[6] + v2[6]) / 3.0f;
    float qy = (v0[7] + v1[7] + v2[7]) / 3.0f;
    float qz = (v0[8] + v1[8] + v2[8]) / 3.0f;

    prev4[t] = make_float4(qx, qy, qz, 0.0f);
    pos4[t]  = make_float4(px, py, pz, 0.0f);
    nrm4[t]  = make_float4(nx, ny, nz, 0.0f);
}

// ---------------- Kernel 2: chunked ball query ----------------
// thread = query, blockIdx.y = face chunk, blockIdx.z = batch.
// All 64 lanes of a wave read the SAME face each iteration (wave-uniform
// address -> broadcast/scalar load, negligible memory traffic).
// Records first up-to-8 in-radius face indices (ascending) + capped count.
__global__ __launch_bounds__(256) void ballq_kernel(
    const float*  __restrict__ state,    // [NB][N_Q][3] (x_t0)
    const float4* __restrict__ prev4,
    int* __restrict__ slots,             // [(b*N_Q+i)*NCHUNK + c][8]
    int* __restrict__ cnts)              // [(b*N_Q+i)*NCHUNK + c]
{
    int i = blockIdx.x * 256 + threadIdx.x;
    int c = blockIdx.y;
    int b = blockIdx.z;
    if (i >= N_Q) return;

    const float* st = state + (size_t)(b * N_Q + i) * 3;
    float qx = st[0], qy = st[1], qz = st[2];

    const float4* pv = prev4 + (size_t)b * N_F;
    int f0 = c * CHUNK;
    int f1 = f0 + CHUNK;

    int cnt = 0;
    int s0 = 0, s1 = 0, s2 = 0, s3 = 0, s4 = 0, s5 = 0, s6 = 0, s7 = 0;

    for (int f = f0; f < f1; ++f) {
        float4 p = pv[f];                 // wave-uniform load
        float dx = p.x - qx;
        float dy = p.y - qy;
        float dz = p.z - qz;
        float d2 = dx * dx + dy * dy + dz * dz;
        if (d2 < RAD2 && cnt < 8) {
            if      (cnt == 0) s0 = f;
            else if (cnt == 1) s1 = f;
            else if (cnt == 2) s2 = f;
            else if (cnt == 3) s3 = f;
            else if (cnt == 4) s4 = f;
            else if (cnt == 5) s5 = f;
            else if (cnt == 6) s6 = f;
            else               s7 = f;
            cnt++;
        }
    }

    size_t o = (size_t)(b * N_Q + i) * NCHUNK + c;
    cnts[o] = cnt;
    int* sp = slots + o * 8;
    sp[0] = s0; sp[1] = s1; sp[2] = s2; sp[3] = s3;
    sp[4] = s4; sp[5] = s5; sp[6] = s6; sp[7] = s7;
}

// ---------------- Kernel 3: merge chunks (ordered) + loss ----------------
__device__ __forceinline__ float contrib(
    const float4* pp, const float4* nn, int fi,
    float x, float y, float z)
{
    float4 P = pp[fi];
    float4 Nn = nn[fi];
    float d = (x - P.x) * Nn.x + (y - P.y) * Nn.y + (z - P.z) * Nn.z;
    float ip = fmaxf(THRESH - d, 0.0f);
    return ip * ip * ip;
}

__global__ __launch_bounds__(256) void loss_kernel(
    const float*  __restrict__ pred,     // [NB][N_Q][3] (x_t1)
    const float4* __restrict__ pos4,
    const float4* __restrict__ nrm4,
    const int* __restrict__ slots,
    const int* __restrict__ cnts,
    float* __restrict__ out)
{
    int i = blockIdx.x * 256 + threadIdx.x;
    int b = blockIdx.z;

    float lsum = 0.0f;
    if (i < N_Q) {
        const float* pr = pred + (size_t)(b * N_Q + i) * 3;
        float x = pr[0], y = pr[1], z = pr[2];

        size_t qo = (size_t)(b * N_Q + i) * NCHUNK;
        int total = 0;
        int t0 = 0, t1 = 0, t2 = 0, t3 = 0, t4 = 0, t5 = 0, t6 = 0, t7 = 0;

        #pragma unroll
        for (int c = 0; c < NCHUNK; ++c) {
            int cc = cnts[qo + c];
            const int* sp = slots + (qo + c) * 8;
            #pragma unroll
            for (int k = 0; k < 8; ++k) {
                if (k < cc && total < 8) {
                    int fi = sp[k];
                    if      (total == 0) t0 = fi;
                    else if (total == 1) t1 = fi;
                    else if (total == 2) t2 = fi;
                    else if (total == 3) t3 = fi;
                    else if (total == 4) t4 = fi;
                    else if (total == 5) t5 = fi;
                    else if (total == 6) t6 = fi;
                    else                 t7 = fi;
                    total++;
                }
            }
        }

        const float4* pp = pos4 + (size_t)b * N_F;
        const float4* nn = nrm4 + (size_t)b * N_F;

        // slot k: k < total ? t_k : t0   (t0 == 0 when total == 0, matching
        // the reference's argsort fallback to index 0)
        lsum += contrib(pp, nn, t0, x, y, z);
        lsum += contrib(pp, nn, (total > 1) ? t1 : t0, x, y, z);
        lsum += contrib(pp, nn, (total > 2) ? t2 : t0, x, y, z);
        lsum += contrib(pp, nn, (total > 3) ? t3 : t0, x, y, z);
        lsum += contrib(pp, nn, (total > 4) ? t4 : t0, x, y, z);
        lsum += contrib(pp, nn, (total > 5) ? t5 : t0, x, y, z);
        lsum += contrib(pp, nn, (total > 6) ? t6 : t0, x, y, z);
        lsum += contrib(pp, nn, (total > 7) ? t7 : t0, x, y, z);
    }

    // block reduction (all threads participate; inactive lanes hold 0)
    for (int off = 32; off > 0; off >>= 1)
        lsum += __shfl_down(lsum, off);
    __shared__ float wsum[4];
    int lane = threadIdx.x & 63;
    int w = threadIdx.x >> 6;
    if (lane == 0) wsum[w] = lsum;
    __syncthreads();
    if (threadIdx.x == 0) {
        float s = wsum[0] + wsum[1] + wsum[2] + wsum[3];
        atomicAdd(out, s * SCALE);
    }
}

extern "C" void kernel_launch(void* const* d_in, const int* in_sizes, int n_in,
                              void* d_out, int out_size, void* d_ws, size_t ws_size,
                              hipStream_t stream) {
    const float* pred    = (const float*)d_in[0];
    const float* state   = (const float*)d_in[1];
    const float* h_state = (const float*)d_in[2];
    const int*   h_faces = (const int*)d_in[3];
    float* out = (float*)d_out;

    // workspace layout
    float4* prev4 = (float4*)d_ws;                    // NB*N_F
    float4* pos4  = prev4 + NB * N_F;                 // NB*N_F
    float4* nrm4  = pos4  + NB * N_F;                 // NB*N_F
    int* cnts  = (int*)(nrm4 + NB * N_F);             // NB*N_Q*NCHUNK
    int* slots = cnts + (size_t)NB * N_Q * NCHUNK;    // NB*N_Q*NCHUNK*8

    hipMemsetAsync(d_out, 0, sizeof(float), stream);

    face_kernel<<<dim3((NB * N_F + 255) / 256), 256, 0, stream>>>(
        h_state, h_faces, prev4, pos4, nrm4);

    dim3 g2((N_Q + 255) / 256, NCHUNK, NB);
    ballq_kernel<<<g2, 256, 0, stream>>>(state, prev4, slots, cnts);

    dim3 g3((N_Q + 255) / 256, 1, NB);
    loss_kernel<<<g3, 256, 0, stream>>>(pred, pos4, nrm4, slots, cnts, out);
}

// Round 2
// 283.547 us; speedup vs baseline: 1.2136x; 1.2136x over previous
//
#include <hip/hip_runtime.h>
#include <limits.h>

#define NB      2
#define N_Q     20000
#define M_V     6890
#define N_F     13776
#define NBF     (NB * N_F)          // 27552
#define RAD2    0.01f               // 0.1^2
#define THRESH  0.001f
#define EPSN    1e-7f
#define SCALE   (1.0f / (float)(NB * N_Q))

// grid
#define GDIM    64
#define NCELLS  (GDIM * GDIM * GDIM)        // 262144
#define T_CELLS (NB * NCELLS)               // 524288
#define H_INV   5.0f                        // h = 0.2 >= radius
#define ORG     (-6.4f)

// scan config: 256 blocks x 256 threads x 8 elems = 524288 exactly
#define SCAN_BLOCKS 256
#define EPT 8
#define EPB 2048

__device__ __forceinline__ int cell_coord(float x) {
    int g = (int)floorf((x - ORG) * H_INV);
    return min(max(g, 0), GDIM - 1);
}

// ---------------- Kernel 1: per-face precompute + histogram ----------------
__global__ __launch_bounds__(256) void face_kernel(
    const float* __restrict__ h_state,   // [NB][M_V][9]
    const int*   __restrict__ h_faces,   // [NB][N_F][3]
    float4* __restrict__ prev4,
    float4* __restrict__ pos4,
    float4* __restrict__ nrm4,
    int* __restrict__ cellid,
    int* __restrict__ cellCnt)
{
    int t = blockIdx.x * 256 + threadIdx.x;
    if (t >= NBF) return;
    int b = t / N_F;
    const int* fc = h_faces + (size_t)t * 3;
    int i0 = fc[0], i1 = fc[1], i2 = fc[2];
    const float* hs = h_state + (size_t)b * M_V * 9;

    const float* v0 = hs + (size_t)i0 * 9;
    const float* v1 = hs + (size_t)i1 * 9;
    const float* v2 = hs + (size_t)i2 * 9;

    float ax = v0[0], ay = v0[1], az = v0[2];
    float bx = v1[0], by = v1[1], bz = v1[2];
    float cx = v2[0], cy = v2[1], cz = v2[2];

    float px = (ax + bx + cx) / 3.0f;
    float py = (ay + by + cy) / 3.0f;
    float pz = (az + bz + cz) / 3.0f;

    float e1x = bx - ax, e1y = by - ay, e1z = bz - az;
    float e2x = cx - ax, e2y = cy - ay, e2z = cz - az;
    float nx = e1y * e2z - e1z * e2y;
    float ny = e1z * e2x - e1x * e2z;
    float nz = e1x * e2y - e1y * e2x;
    float nrm = sqrtf(nx * nx + ny * ny + nz * nz);
    float den = fmaxf(nrm, EPSN);
    nx /= den; ny /= den; nz /= den;

    float qx = (v0[6] + v1[6] + v2[6]) / 3.0f;
    float qy = (v0[7] + v1[7] + v2[7]) / 3.0f;
    float qz = (v0[8] + v1[8] + v2[8]) / 3.0f;

    prev4[t] = make_float4(qx, qy, qz, 0.0f);
    pos4[t]  = make_float4(px, py, pz, 0.0f);
    nrm4[t]  = make_float4(nx, ny, nz, 0.0f);

    int gx = cell_coord(qx), gy = cell_coord(qy), gz = cell_coord(qz);
    int cid = b * NCELLS + (gz * GDIM + gy) * GDIM + gx;
    cellid[t] = cid;
    atomicAdd(&cellCnt[cid], 1);
}

// ---------------- Scan (exclusive) over T_CELLS ----------------
__global__ __launch_bounds__(256) void scan1_kernel(
    const int* __restrict__ cnt, int* __restrict__ out, int* __restrict__ blockSums)
{
    __shared__ int sm[256];
    int t = threadIdx.x;
    size_t base = (size_t)blockIdx.x * EPB + (size_t)t * EPT;
    int v[EPT];
    int s = 0;
    #pragma unroll
    for (int k = 0; k < EPT; ++k) { v[k] = cnt[base + k]; s += v[k]; }
    sm[t] = s;
    __syncthreads();
    #pragma unroll
    for (int off = 1; off < 256; off <<= 1) {
        int add = (t >= off) ? sm[t - off] : 0;
        __syncthreads();
        sm[t] += add;
        __syncthreads();
    }
    int pref = sm[t] - s;   // exclusive within block
    #pragma unroll
    for (int k = 0; k < EPT; ++k) { out[base + k] = pref; pref += v[k]; }
    if (t == 255) blockSums[blockIdx.x] = sm[255];
}

__global__ __launch_bounds__(256) void scan2_kernel(int* __restrict__ blockSums)
{
    __shared__ int sm[256];
    int t = threadIdx.x;
    int s = blockSums[t];
    sm[t] = s;
    __syncthreads();
    #pragma unroll
    for (int off = 1; off < 256; off <<= 1) {
        int add = (t >= off) ? sm[t - off] : 0;
        __syncthreads();
        sm[t] += add;
        __syncthreads();
    }
    blockSums[t] = sm[t] - s;   // exclusive block offsets
}

__global__ __launch_bounds__(256) void scan3_kernel(
    int* __restrict__ start, const int* __restrict__ blockOffs)
{
    int t = threadIdx.x;
    size_t base = (size_t)blockIdx.x * EPB + (size_t)t * EPT;
    int off = blockOffs[blockIdx.x];
    #pragma unroll
    for (int k = 0; k < EPT; ++k) start[base + k] += off;
    if (blockIdx.x == 0 && t == 0) start[T_CELLS] = NBF;
}

// ---------------- Scatter (counting-sort placement) ----------------
__global__ __launch_bounds__(256) void scatter_kernel(
    const int* __restrict__ cellid, int* __restrict__ cellCnt,
    const int* __restrict__ start, int* __restrict__ faceSorted)
{
    int t = blockIdx.x * 256 + threadIdx.x;
    if (t >= NBF) return;
    int c = cellid[t];
    int old = atomicSub(&cellCnt[c], 1);      // old in [1..cnt]
    faceSorted[start[c] + old - 1] = t;       // global face slot
}

// ---------------- Query + loss ----------------
__device__ __forceinline__ float contrib(
    const float4* __restrict__ pos4, const float4* __restrict__ nrm4, int fi,
    float x, float y, float z)
{
    float4 P = pos4[fi];
    float4 Nn = nrm4[fi];
    float d = (x - P.x) * Nn.x + (y - P.y) * Nn.y + (z - P.z) * Nn.z;
    float ip = fmaxf(THRESH - d, 0.0f);
    return ip * ip * ip;
}

#define CSW(a, b) { int _mn = min(a, b); int _mx = max(a, b); a = _mn; b = _mx; }

__global__ __launch_bounds__(64) void query_kernel(
    const float*  __restrict__ state,    // x_t0 queries
    const float*  __restrict__ pred,     // x_t1 for loss
    const float4* __restrict__ prev4,
    const float4* __restrict__ pos4,
    const float4* __restrict__ nrm4,
    const int* __restrict__ start,
    const int* __restrict__ faceSorted,
    float* __restrict__ out)
{
    int i = blockIdx.x * 64 + threadIdx.x;
    int b = blockIdx.z;

    float lsum = 0.0f;
    if (i < N_Q) {
        const float* st = state + (size_t)(b * N_Q + i) * 3;
        float qx = st[0], qy = st[1], qz = st[2];
        const float* pr = pred + (size_t)(b * N_Q + i) * 3;
        float x = pr[0], y = pr[1], z = pr[2];

        int cx = cell_coord(qx), cy = cell_coord(qy), cz = cell_coord(qz);

        int s0 = INT_MAX, s1 = INT_MAX, s2 = INT_MAX, s3 = INT_MAX;
        int s4 = INT_MAX, s5 = INT_MAX, s6 = INT_MAX, s7 = INT_MAX;
        int cnt = 0;

        #pragma unroll
        for (int dz = -1; dz <= 1; ++dz)
        #pragma unroll
        for (int dy = -1; dy <= 1; ++dy)
        #pragma unroll
        for (int dx = -1; dx <= 1; ++dx) {
            int gx = cx + dx, gy = cy + dy, gz = cz + dz;
            if ((unsigned)gx < (unsigned)GDIM &&
                (unsigned)gy < (unsigned)GDIM &&
                (unsigned)gz < (unsigned)GDIM) {
                int c = b * NCELLS + (gz * GDIM + gy) * GDIM + gx;
                int j0 = start[c];
                int j1 = start[c + 1];
                for (int j = j0; j < j1; ++j) {
                    int tf = faceSorted[j];
                    float4 p = prev4[tf];
                    float ddx = p.x - qx, ddy = p.y - qy, ddz = p.z - qz;
                    float d2 = ddx * ddx + ddy * ddy + ddz * ddz;
                    if (d2 < RAD2) {
                        ++cnt;
                        // keep 8 smallest global indices, sorted ascending
                        if (tf < s7) s7 = tf;
                        CSW(s6, s7); CSW(s5, s6); CSW(s4, s5); CSW(s3, s4);
                        CSW(s2, s3); CSW(s1, s2); CSW(s0, s1);
                    }
                }
            }
        }

        if (cnt == 0) s0 = b * N_F;          // reference argsort fallback -> face 0
        s1 = (cnt > 1) ? s1 : s0;
        s2 = (cnt > 2) ? s2 : s0;
        s3 = (cnt > 3) ? s3 : s0;
        s4 = (cnt > 4) ? s4 : s0;
        s5 = (cnt > 5) ? s5 : s0;
        s6 = (cnt > 6) ? s6 : s0;
        s7 = (cnt > 7) ? s7 : s0;

        lsum += contrib(pos4, nrm4, s0, x, y, z);
        lsum += contrib(pos4, nrm4, s1, x, y, z);
        lsum += contrib(pos4, nrm4, s2, x, y, z);
        lsum += contrib(pos4, nrm4, s3, x, y, z);
        lsum += contrib(pos4, nrm4, s4, x, y, z);
        lsum += contrib(pos4, nrm4, s5, x, y, z);
        lsum += contrib(pos4, nrm4, s6, x, y, z);
        lsum += contrib(pos4, nrm4, s7, x, y, z);
    }

    // single-wave block reduction
    for (int off = 32; off > 0; off >>= 1)
        lsum += __shfl_down(lsum, off);
    if (threadIdx.x == 0)
        atomicAdd(out, lsum * SCALE);
}

extern "C" void kernel_launch(void* const* d_in, const int* in_sizes, int n_in,
                              void* d_out, int out_size, void* d_ws, size_t ws_size,
                              hipStream_t stream) {
    const float* pred    = (const float*)d_in[0];
    const float* state   = (const float*)d_in[1];
    const float* h_state = (const float*)d_in[2];
    const int*   h_faces = (const int*)d_in[3];
    float* out = (float*)d_out;

    // workspace layout (~5.7 MB, < 13.2 MB proven in R1)
    float4* prev4   = (float4*)d_ws;                 // NBF
    float4* pos4    = prev4 + NBF;                   // NBF
    float4* nrm4    = pos4 + NBF;                    // NBF
    int* cellid     = (int*)(nrm4 + NBF);            // NBF
    int* cellCnt    = cellid + NBF;                  // T_CELLS
    int* startArr   = cellCnt + T_CELLS;             // T_CELLS + 1
    int* blockSums  = startArr + T_CELLS + 1;        // SCAN_BLOCKS
    int* faceSorted = blockSums + SCAN_BLOCKS;       // NBF

    hipMemsetAsync(out, 0, sizeof(float), stream);
    hipMemsetAsync(cellCnt, 0, (size_t)T_CELLS * sizeof(int), stream);

    face_kernel<<<dim3((NBF + 255) / 256), 256, 0, stream>>>(
        h_state, h_faces, prev4, pos4, nrm4, cellid, cellCnt);

    scan1_kernel<<<dim3(SCAN_BLOCKS), 256, 0, stream>>>(cellCnt, startArr, blockSums);
    scan2_kernel<<<dim3(1), 256, 0, stream>>>(blockSums);
    scan3_kernel<<<dim3(SCAN_BLOCKS), 256, 0, stream>>>(startArr, blockSums);

    scatter_kernel<<<dim3((NBF + 255) / 256), 256, 0, stream>>>(
        cellid, cellCnt, startArr, faceSorted);

    dim3 gq((N_Q + 63) / 64, 1, NB);
    query_kernel<<<gq, 64, 0, stream>>>(
        state, pred, prev4, pos4, nrm4, startArr, faceSorted, out);
}

// Round 3
// 85.124 us; speedup vs baseline: 4.0424x; 3.3310x over previous
//
#include <hip/hip_runtime.h>
#include <limits.h>

#define NB      2
#define N_Q     20000
#define M_V     6890
#define N_F     13776
#define NBF     (NB * N_F)          // 27552
#define RAD2    0.01f               // 0.1^2
#define THRESH  0.001f
#define EPSN    1e-7f
#define SCALE   (1.0f / (float)(NB * N_Q))

// grid: 32^3, cell h=0.2 >= radius, span [-3.2, 3.2] (clamped; clamp is a
// contraction so two points within r always land in cells differing by <=1)
#define GDIM    32
#define NCELLS  (GDIM * GDIM * GDIM)        // 32768
#define T_CELLS (NB * NCELLS)               // 65536
#define H_INV   5.0f
#define ORG     (-3.2f)

// scan config: 32 blocks x 256 threads x 8 elems = 65536 exactly
#define SCAN_BLOCKS 32
#define EPT 8
#define EPB 2048

__device__ __forceinline__ int cell_coord(float x) {
    int g = (int)floorf((x - ORG) * H_INV);
    return min(max(g, 0), GDIM - 1);
}

// ---------------- Kernel 1: per-face precompute + histogram ----------------
__global__ __launch_bounds__(256) void face_kernel(
    const float* __restrict__ h_state,   // [NB][M_V][9]
    const int*   __restrict__ h_faces,   // [NB][N_F][3]
    float4* __restrict__ prev4,
    float4* __restrict__ pos4,
    float4* __restrict__ nrm4,
    int* __restrict__ cellid,
    int* __restrict__ cellCnt)
{
    int t = blockIdx.x * 256 + threadIdx.x;
    if (t >= NBF) return;
    int b = t / N_F;
    const int* fc = h_faces + (size_t)t * 3;
    int i0 = fc[0], i1 = fc[1], i2 = fc[2];
    const float* hs = h_state + (size_t)b * M_V * 9;

    const float* v0 = hs + (size_t)i0 * 9;
    const float* v1 = hs + (size_t)i1 * 9;
    const float* v2 = hs + (size_t)i2 * 9;

    float ax = v0[0], ay = v0[1], az = v0[2];
    float bx = v1[0], by = v1[1], bz = v1[2];
    float cx = v2[0], cy = v2[1], cz = v2[2];

    float px = (ax + bx + cx) / 3.0f;
    float py = (ay + by + cy) / 3.0f;
    float pz = (az + bz + cz) / 3.0f;

    float e1x = bx - ax, e1y = by - ay, e1z = bz - az;
    float e2x = cx - ax, e2y = cy - ay, e2z = cz - az;
    float nx = e1y * e2z - e1z * e2y;
    float ny = e1z * e2x - e1x * e2z;
    float nz = e1x * e2y - e1y * e2x;
    float nrm = sqrtf(nx * nx + ny * ny + nz * nz);
    float den = fmaxf(nrm, EPSN);
    nx /= den; ny /= den; nz /= den;

    float qx = (v0[6] + v1[6] + v2[6]) / 3.0f;
    float qy = (v0[7] + v1[7] + v2[7]) / 3.0f;
    float qz = (v0[8] + v1[8] + v2[8]) / 3.0f;

    prev4[t] = make_float4(qx, qy, qz, 0.0f);
    pos4[t]  = make_float4(px, py, pz, 0.0f);
    nrm4[t]  = make_float4(nx, ny, nz, 0.0f);

    int gx = cell_coord(qx), gy = cell_coord(qy), gz = cell_coord(qz);
    int cid = b * NCELLS + (gz * GDIM + gy) * GDIM + gx;
    cellid[t] = cid;
    atomicAdd(&cellCnt[cid], 1);
}

// ---------------- Scan (exclusive) over T_CELLS ----------------
__global__ __launch_bounds__(256) void scan1_kernel(
    const int* __restrict__ cnt, int* __restrict__ out, int* __restrict__ blockSums)
{
    __shared__ int sm[256];
    int t = threadIdx.x;
    size_t base = (size_t)blockIdx.x * EPB + (size_t)t * EPT;
    int v[EPT];
    int s = 0;
    #pragma unroll
    for (int k = 0; k < EPT; ++k) { v[k] = cnt[base + k]; s += v[k]; }
    sm[t] = s;
    __syncthreads();
    #pragma unroll
    for (int off = 1; off < 256; off <<= 1) {
        int add = (t >= off) ? sm[t - off] : 0;
        __syncthreads();
        sm[t] += add;
        __syncthreads();
    }
    int pref = sm[t] - s;   // exclusive within block
    #pragma unroll
    for (int k = 0; k < EPT; ++k) { out[base + k] = pref; pref += v[k]; }
    if (t == 255) blockSums[blockIdx.x] = sm[255];
}

__global__ __launch_bounds__(64) void scan2_kernel(int* __restrict__ blockSums)
{
    __shared__ int sm[64];
    int t = threadIdx.x;
    int s = (t < SCAN_BLOCKS) ? blockSums[t] : 0;
    sm[t] = s;
    __syncthreads();
    #pragma unroll
    for (int off = 1; off < 64; off <<= 1) {
        int add = (t >= off) ? sm[t - off] : 0;
        __syncthreads();
        sm[t] += add;
        __syncthreads();
    }
    if (t < SCAN_BLOCKS) blockSums[t] = sm[t] - s;   // exclusive block offsets
}

__global__ __launch_bounds__(256) void scan3_kernel(
    int* __restrict__ start, const int* __restrict__ blockOffs)
{
    int t = threadIdx.x;
    size_t base = (size_t)blockIdx.x * EPB + (size_t)t * EPT;
    int off = blockOffs[blockIdx.x];
    #pragma unroll
    for (int k = 0; k < EPT; ++k) start[base + k] += off;
    if (blockIdx.x == 0 && t == 0) start[T_CELLS] = NBF;
}

// ---------------- Scatter: counting-sort faces; pack pos+id in 16B ----------
__global__ __launch_bounds__(256) void scatter_kernel(
    const int* __restrict__ cellid, int* __restrict__ cellCnt,
    const int* __restrict__ start, const float4* __restrict__ prev4,
    float4* __restrict__ prevSorted4)
{
    int t = blockIdx.x * 256 + threadIdx.x;
    if (t >= NBF) return;
    int c = cellid[t];
    int old = atomicSub(&cellCnt[c], 1);      // old in [1..cnt]
    float4 p = prev4[t];
    p.w = __int_as_float(t);                  // embed global face id
    prevSorted4[start[c] + old - 1] = p;
}

// ---------------- Query + loss ----------------
__device__ __forceinline__ float contrib(
    const float4* __restrict__ pos4, const float4* __restrict__ nrm4, int fi,
    float x, float y, float z)
{
    float4 P = pos4[fi];
    float4 Nn = nrm4[fi];
    float d = (x - P.x) * Nn.x + (y - P.y) * Nn.y + (z - P.z) * Nn.z;
    float ip = fmaxf(THRESH - d, 0.0f);
    return ip * ip * ip;
}

#define CSW(a, b) { int _mn = min(a, b); int _mx = max(a, b); a = _mn; b = _mx; }

// block = 576 threads = 9 waves. Wave r handles neighbor-row r (one (dz,dy)
// pair, 3 x-cells fused into one contiguous span) for 64 queries. Partials
// (count + 8 smallest face ids, sorted) merge in LDS; wave 0 does the loss.
__global__ __launch_bounds__(576) void query_kernel(
    const float*  __restrict__ state,    // x_t0 queries
    const float*  __restrict__ pred,     // x_t1 for loss
    const float4* __restrict__ prevSorted4,
    const float4* __restrict__ pos4,
    const float4* __restrict__ nrm4,
    const int* __restrict__ start,
    float* __restrict__ out)
{
    __shared__ int lds[64][9][9];        // [query][row][s0..s7, cnt]

    int tid  = threadIdx.x;
    int lane = tid & 63;                 // query slot within block
    int r    = tid / 64;                 // neighbor row 0..8
    int b    = blockIdx.z;
    int i    = blockIdx.x * 64 + lane;

    if (i < N_Q) {
        const float* st = state + (size_t)(b * N_Q + i) * 3;
        float qx = st[0], qy = st[1], qz = st[2];
        int cx = cell_coord(qx), cy = cell_coord(qy), cz = cell_coord(qz);

        int dz = r / 3 - 1, dy = r % 3 - 1;
        int gz = cz + dz, gy = cy + dy;

        int s0 = INT_MAX, s1 = INT_MAX, s2 = INT_MAX, s3 = INT_MAX;
        int s4 = INT_MAX, s5 = INT_MAX, s6 = INT_MAX, s7 = INT_MAX;
        int cnt = 0;

        if ((unsigned)gz < (unsigned)GDIM && (unsigned)gy < (unsigned)GDIM) {
            int xlo = max(cx - 1, 0);
            int xhi = min(cx + 1, GDIM - 1);
            int cbase = b * NCELLS + (gz * GDIM + gy) * GDIM;
            int j0 = start[cbase + xlo];
            int j1 = start[cbase + xhi + 1];
            for (int j = j0; j < j1; ++j) {
                float4 p = prevSorted4[j];   // one independent 16B load/test
                float ddx = p.x - qx, ddy = p.y - qy, ddz = p.z - qz;
                float d2 = ddx * ddx + ddy * ddy + ddz * ddz;
                if (d2 < RAD2) {
                    ++cnt;
                    int tf = __float_as_int(p.w);
                    if (tf < s7) {
                        s7 = tf;
                        CSW(s6, s7); CSW(s5, s6); CSW(s4, s5); CSW(s3, s4);
                        CSW(s2, s3); CSW(s1, s2); CSW(s0, s1);
                    }
                }
            }
        }

        int* L = &lds[lane][r][0];
        L[0] = s0; L[1] = s1; L[2] = s2; L[3] = s3;
        L[4] = s4; L[5] = s5; L[6] = s6; L[7] = s7;
        L[8] = cnt;
    }
    __syncthreads();

    float lsum = 0.0f;
    if (tid < 64 && i < N_Q) {
        int s0 = INT_MAX, s1 = INT_MAX, s2 = INT_MAX, s3 = INT_MAX;
        int s4 = INT_MAX, s5 = INT_MAX, s6 = INT_MAX, s7 = INT_MAX;
        int cnt = 0;
        #pragma unroll
        for (int rr = 0; rr < 9; ++rr) {
            const int* L = &lds[lane][rr][0];
            cnt += L[8];
            #pragma unroll
            for (int k = 0; k < 8; ++k) {
                int v = L[k];
                if (v < s7) {
                    s7 = v;
                    CSW(s6, s7); CSW(s5, s6); CSW(s4, s5); CSW(s3, s4);
                    CSW(s2, s3); CSW(s1, s2); CSW(s0, s1);
                }
            }
        }

        if (cnt == 0) s0 = b * N_F;          // argsort fallback -> face 0 of batch
        s1 = (cnt > 1) ? s1 : s0;
        s2 = (cnt > 2) ? s2 : s0;
        s3 = (cnt > 3) ? s3 : s0;
        s4 = (cnt > 4) ? s4 : s0;
        s5 = (cnt > 5) ? s5 : s0;
        s6 = (cnt > 6) ? s6 : s0;
        s7 = (cnt > 7) ? s7 : s0;

        const float* pr = pred + (size_t)(b * N_Q + i) * 3;
        float x = pr[0], y = pr[1], z = pr[2];

        lsum += contrib(pos4, nrm4, s0, x, y, z);
        lsum += contrib(pos4, nrm4, s1, x, y, z);
        lsum += contrib(pos4, nrm4, s2, x, y, z);
        lsum += contrib(pos4, nrm4, s3, x, y, z);
        lsum += contrib(pos4, nrm4, s4, x, y, z);
        lsum += contrib(pos4, nrm4, s5, x, y, z);
        lsum += contrib(pos4, nrm4, s6, x, y, z);
        lsum += contrib(pos4, nrm4, s7, x, y, z);
    }

    // wave-0 reduction + one atomic
    if (tid < 64) {
        for (int off = 32; off > 0; off >>= 1)
            lsum += __shfl_down(lsum, off);
        if (tid == 0)
            atomicAdd(out, lsum * SCALE);
    }
}

extern "C" void kernel_launch(void* const* d_in, const int* in_sizes, int n_in,
                              void* d_out, int out_size, void* d_ws, size_t ws_size,
                              hipStream_t stream) {
    const float* pred    = (const float*)d_in[0];
    const float* state   = (const float*)d_in[1];
    const float* h_state = (const float*)d_in[2];
    const int*   h_faces = (const int*)d_in[3];
    float* out = (float*)d_out;

    // workspace layout (~2.4 MB)
    float4* prev4       = (float4*)d_ws;             // NBF
    float4* pos4        = prev4 + NBF;               // NBF
    float4* nrm4        = pos4 + NBF;                // NBF
    float4* prevSorted4 = nrm4 + NBF;                // NBF
    int* cellid         = (int*)(prevSorted4 + NBF); // NBF
    int* cellCnt        = cellid + NBF;              // T_CELLS
    int* startArr       = cellCnt + T_CELLS;         // T_CELLS + 1
    int* blockSums      = startArr + T_CELLS + 1;    // SCAN_BLOCKS

    hipMemsetAsync(out, 0, sizeof(float), stream);
    hipMemsetAsync(cellCnt, 0, (size_t)T_CELLS * sizeof(int), stream);

    face_kernel<<<dim3((NBF + 255) / 256), 256, 0, stream>>>(
        h_state, h_faces, prev4, pos4, nrm4, cellid, cellCnt);

    scan1_kernel<<<dim3(SCAN_BLOCKS), 256, 0, stream>>>(cellCnt, startArr, blockSums);
    scan2_kernel<<<dim3(1), 64, 0, stream>>>(blockSums);
    scan3_kernel<<<dim3(SCAN_BLOCKS), 256, 0, stream>>>(startArr, blockSums);

    scatter_kernel<<<dim3((NBF + 255) / 256), 256, 0, stream>>>(
        cellid, cellCnt, startArr, prev4, prevSorted4);

    dim3 gq((N_Q + 63) / 64, 1, NB);
    query_kernel<<<gq, 576, 0, stream>>>(
        state, pred, prevSorted4, pos4, nrm4, startArr, out);
}

// Round 4
// 65.036 us; speedup vs baseline: 5.2910x; 1.3089x over previous
//
#include <hip/hip_runtime.h>
#include <limits.h>

#define NB      2
#define N_Q     20000
#define NBQ     (NB * N_Q)          // 40000
#define M_V     6890
#define N_F     13776
#define NBF     (NB * N_F)          // 27552
#define RAD2    0.01f               // 0.1^2
#define THRESH  0.001f
#define EPSN    1e-7f
#define SCALE   (1.0f / (float)(NB * N_Q))

// grid: 16^3, cell h=0.2 >= radius, span [-1.6, 1.6] clamped.
// clamp is 1-Lipschitz monotone per axis, so any pair within r=0.1 < h
// lands in cells differing by <=1 per axis. Far-tail points clamp into
// boundary cells, which hold almost no faces (face centroid sigma≈0.58).
#define GDIM    16
#define NCELLS  (GDIM * GDIM * GDIM)        // 4096
#define T_CELLS (NB * NCELLS)               // 8192
#define H_INV   5.0f
#define ORG     (-1.6f)

#define QPB     4                   // queries per block (1 per wave)
#define QBLOCKS (NBQ / QPB)         // 10000 exactly

__device__ __forceinline__ int cell_coord(float x) {
    int g = (int)floorf((x - ORG) * H_INV);
    return min(max(g, 0), GDIM - 1);
}

__device__ __forceinline__ int wave_min_i(int v) {
    #pragma unroll
    for (int m = 32; m; m >>= 1) v = min(v, __shfl_xor(v, m));
    return v;
}
__device__ __forceinline__ int wave_add_i(int v) {
    #pragma unroll
    for (int m = 32; m; m >>= 1) v += __shfl_xor(v, m);
    return v;
}
__device__ __forceinline__ float wave_add_f(float v) {
    #pragma unroll
    for (int m = 32; m; m >>= 1) v += __shfl_xor(v, m);
    return v;
}

// ---------------- Kernel 1: per-face precompute + histogram ----------------
__global__ __launch_bounds__(256) void face_kernel(
    const float* __restrict__ h_state,   // [NB][M_V][9]
    const int*   __restrict__ h_faces,   // [NB][N_F][3]
    float4* __restrict__ prev4,
    float4* __restrict__ pos4,
    float4* __restrict__ nrm4,
    int* __restrict__ cellid,
    int* __restrict__ cellCnt)
{
    int t = blockIdx.x * 256 + threadIdx.x;
    if (t >= NBF) return;
    int b = t / N_F;
    const int* fc = h_faces + (size_t)t * 3;
    int i0 = fc[0], i1 = fc[1], i2 = fc[2];
    const float* hs = h_state + (size_t)b * M_V * 9;

    const float* v0 = hs + (size_t)i0 * 9;
    const float* v1 = hs + (size_t)i1 * 9;
    const float* v2 = hs + (size_t)i2 * 9;

    float ax = v0[0], ay = v0[1], az = v0[2];
    float bx = v1[0], by = v1[1], bz = v1[2];
    float cx = v2[0], cy = v2[1], cz = v2[2];

    float px = (ax + bx + cx) / 3.0f;
    float py = (ay + by + cy) / 3.0f;
    float pz = (az + bz + cz) / 3.0f;

    float e1x = bx - ax, e1y = by - ay, e1z = bz - az;
    float e2x = cx - ax, e2y = cy - ay, e2z = cz - az;
    float nx = e1y * e2z - e1z * e2y;
    float ny = e1z * e2x - e1x * e2z;
    float nz = e1x * e2y - e1y * e2x;
    float nrm = sqrtf(nx * nx + ny * ny + nz * nz);
    float den = fmaxf(nrm, EPSN);
    nx /= den; ny /= den; nz /= den;

    float qx = (v0[6] + v1[6] + v2[6]) / 3.0f;
    float qy = (v0[7] + v1[7] + v2[7]) / 3.0f;
    float qz = (v0[8] + v1[8] + v2[8]) / 3.0f;

    prev4[t] = make_float4(qx, qy, qz, 0.0f);
    pos4[t]  = make_float4(px, py, pz, 0.0f);
    nrm4[t]  = make_float4(nx, ny, nz, 0.0f);

    int gx = cell_coord(qx), gy = cell_coord(qy), gz = cell_coord(qz);
    int cid = b * NCELLS + (gz * GDIM + gy) * GDIM + gx;
    cellid[t] = cid;
    atomicAdd(&cellCnt[cid], 1);
}

// ---------------- Kernel 2: single-block exclusive scan over 8192 ----------
__global__ __launch_bounds__(256) void scan_kernel(
    const int* __restrict__ cnt, int* __restrict__ start)
{
    __shared__ int sm[256];
    int t = threadIdx.x;
    int base = t * 32;
    int v[32];
    int s = 0;
    #pragma unroll
    for (int k = 0; k < 32; ++k) { v[k] = cnt[base + k]; s += v[k]; }
    sm[t] = s;
    __syncthreads();
    #pragma unroll
    for (int off = 1; off < 256; off <<= 1) {
        int add = (t >= off) ? sm[t - off] : 0;
        __syncthreads();
        sm[t] += add;
        __syncthreads();
    }
    int pref = sm[t] - s;   // exclusive
    #pragma unroll
    for (int k = 0; k < 32; ++k) { start[base + k] = pref; pref += v[k]; }
    if (t == 255) start[T_CELLS] = NBF;
}

// ---------------- Kernel 3: scatter faces; pack pos+id into 16B ------------
__global__ __launch_bounds__(256) void scatter_kernel(
    const int* __restrict__ cellid, int* __restrict__ cellCnt,
    const int* __restrict__ start, const float4* __restrict__ prev4,
    float4* __restrict__ prevSorted4)
{
    int t = blockIdx.x * 256 + threadIdx.x;
    if (t >= NBF) return;
    int c = cellid[t];
    int old = atomicSub(&cellCnt[c], 1);      // old in [1..cnt]
    float4 p = prev4[t];
    p.w = __int_as_float(t);                  // embed global face id
    prevSorted4[start[c] + old - 1] = p;
}

// ---------------- Kernel 4: one wave per query -----------------------------
#define CSW(a, b) { int _mn = min(a, b); int _mx = max(a, b); a = _mn; b = _mx; }

__global__ __launch_bounds__(256) void query_kernel(
    const float*  __restrict__ state,    // x_t0 queries
    const float*  __restrict__ pred,     // x_t1 for loss
    const float4* __restrict__ prevSorted4,
    const float4* __restrict__ pos4,
    const float4* __restrict__ nrm4,
    const int* __restrict__ start,
    float* __restrict__ partials)
{
    int tid  = threadIdx.x;
    int lane = tid & 63;
    int w    = tid >> 6;
    int q    = blockIdx.x * QPB + w;     // always < NBQ (exact grid)
    int b    = (q >= N_Q) ? 1 : 0;

    const float* st = state + (size_t)q * 3;
    float qx = st[0], qy = st[1], qz = st[2];
    int cx = cell_coord(qx), cy = cell_coord(qy), cz = cell_coord(qz);

    // 9 neighbor rows (dz,dy), x-range fused into one contiguous span each
    int cum[10];
    int off[9];
    cum[0] = 0;
    int xlo = max(cx - 1, 0);
    int xhi = min(cx + 1, GDIM - 1);
    #pragma unroll
    for (int r = 0; r < 9; ++r) {
        int gz = cz + r / 3 - 1;
        int gy = cy + r % 3 - 1;
        int len = 0, j0 = 0;
        if (((unsigned)gz < (unsigned)GDIM) & ((unsigned)gy < (unsigned)GDIM)) {
            int cbase = b * NCELLS + (gz * GDIM + gy) * GDIM;
            j0  = start[cbase + xlo];
            len = start[cbase + xhi + 1] - j0;
        }
        off[r] = j0 - cum[r];
        cum[r + 1] = cum[r] + len;
    }
    int C = cum[9];

    // lanes split the candidate union; per-lane 8-smallest insertion list
    int s0 = INT_MAX, s1 = INT_MAX, s2 = INT_MAX, s3 = INT_MAX;
    int s4 = INT_MAX, s5 = INT_MAX, s6 = INT_MAX, s7 = INT_MAX;
    int cnt = 0;

    int iters = (C + 63) >> 6;
    for (int it = 0; it < iters; ++it) {
        int k = (it << 6) + lane;
        int addr = off[0] + k;
        #pragma unroll
        for (int r = 1; r < 9; ++r)
            addr = (k >= cum[r]) ? off[r] + k : addr;
        if (k < C) {
            float4 p = prevSorted4[addr];
            float ddx = p.x - qx, ddy = p.y - qy, ddz = p.z - qz;
            float d2 = ddx * ddx + ddy * ddy + ddz * ddz;
            if (d2 < RAD2) {
                ++cnt;
                int tf = __float_as_int(p.w);
                if (tf < s7) {
                    s7 = tf;
                    CSW(s6, s7); CSW(s5, s6); CSW(s4, s5); CSW(s3, s4);
                    CSW(s2, s3); CSW(s1, s2); CSW(s0, s1);
                }
            }
        }
    }

    // merge across lanes: e rounds of wave-min + pop (ids unique -> 1 pop)
    int cnt_tot = wave_add_i(cnt);
    int e = min(cnt_tot, 8);
    int t0 = 0, t1 = 0, t2 = 0, t3 = 0, t4 = 0, t5 = 0, t6 = 0, t7 = 0;

#define EXTRACT(K, TK)                                                   \
    if (K < e) {                                                         \
        int m = wave_min_i(s0);                                          \
        TK = m;                                                          \
        bool p = (s0 == m);                                              \
        s0 = p ? s1 : s0; s1 = p ? s2 : s1; s2 = p ? s3 : s2;            \
        s3 = p ? s4 : s3; s4 = p ? s5 : s4; s5 = p ? s6 : s5;            \
        s6 = p ? s7 : s6; s7 = p ? INT_MAX : s7;                         \
    }
    EXTRACT(0, t0) EXTRACT(1, t1) EXTRACT(2, t2) EXTRACT(3, t3)
    EXTRACT(4, t4) EXTRACT(5, t5) EXTRACT(6, t6) EXTRACT(7, t7)
#undef EXTRACT

    if (cnt_tot == 0) t0 = b * N_F;      // argsort fallback -> face 0 of batch
    t1 = (e > 1) ? t1 : t0;
    t2 = (e > 2) ? t2 : t0;
    t3 = (e > 3) ? t3 : t0;
    t4 = (e > 4) ? t4 : t0;
    t5 = (e > 5) ? t5 : t0;
    t6 = (e > 6) ? t6 : t0;
    t7 = (e > 7) ? t7 : t0;

    // lanes 0..7 compute the 8 contributions in parallel
    int v = t0;
    v = (lane == 1) ? t1 : v;
    v = (lane == 2) ? t2 : v;
    v = (lane == 3) ? t3 : v;
    v = (lane == 4) ? t4 : v;
    v = (lane == 5) ? t5 : v;
    v = (lane == 6) ? t6 : v;
    v = (lane == 7) ? t7 : v;

    const float* pr = pred + (size_t)q * 3;
    float x = pr[0], y = pr[1], z = pr[2];
    float4 P  = pos4[v];
    float4 Nn = nrm4[v];
    float d = (x - P.x) * Nn.x + (y - P.y) * Nn.y + (z - P.z) * Nn.z;
    float ip = fmaxf(THRESH - d, 0.0f);
    float c = ip * ip * ip;
    c = (lane < 8) ? c : 0.0f;

    float lsum = wave_add_f(c);          // per-query loss (uniform in wave)

    __shared__ float ws[QPB];
    if (lane == 0) ws[w] = lsum;
    __syncthreads();
    if (tid == 0)
        partials[blockIdx.x] = ws[0] + ws[1] + ws[2] + ws[3];
}

// ---------------- Kernel 5: final reduce -----------------------------------
__global__ __launch_bounds__(1024) void reduce_kernel(
    const float* __restrict__ partials, float* __restrict__ out)
{
    float s = 0.0f;
    for (int i = threadIdx.x; i < QBLOCKS; i += 1024)
        s += partials[i];
    s = wave_add_f(s);
    __shared__ float ws[16];
    int lane = threadIdx.x & 63, w = threadIdx.x >> 6;
    if (lane == 0) ws[w] = s;
    __syncthreads();
    if (threadIdx.x == 0) {
        float t = 0.0f;
        #pragma unroll
        for (int i = 0; i < 16; ++i) t += ws[i];
        out[0] = t * SCALE;
    }
}

extern "C" void kernel_launch(void* const* d_in, const int* in_sizes, int n_in,
                              void* d_out, int out_size, void* d_ws, size_t ws_size,
                              hipStream_t stream) {
    const float* pred    = (const float*)d_in[0];
    const float* state   = (const float*)d_in[1];
    const float* h_state = (const float*)d_in[2];
    const int*   h_faces = (const int*)d_in[3];
    float* out = (float*)d_out;

    // workspace layout (~2.1 MB)
    float4* prev4       = (float4*)d_ws;             // NBF
    float4* pos4        = prev4 + NBF;               // NBF
    float4* nrm4        = pos4 + NBF;                // NBF
    float4* prevSorted4 = nrm4 + NBF;                // NBF
    int* cellid         = (int*)(prevSorted4 + NBF); // NBF
    int* cellCnt        = cellid + NBF;              // T_CELLS
    int* startArr       = cellCnt + T_CELLS;         // T_CELLS + 1
    float* partials     = (float*)(startArr + T_CELLS + 1); // QBLOCKS

    hipMemsetAsync(cellCnt, 0, (size_t)T_CELLS * sizeof(int), stream);

    face_kernel<<<dim3((NBF + 255) / 256), 256, 0, stream>>>(
        h_state, h_faces, prev4, pos4, nrm4, cellid, cellCnt);

    scan_kernel<<<dim3(1), 256, 0, stream>>>(cellCnt, startArr);

    scatter_kernel<<<dim3((NBF + 255) / 256), 256, 0, stream>>>(
        cellid, cellCnt, startArr, prev4, prevSorted4);

    query_kernel<<<dim3(QBLOCKS), 256, 0, stream>>>(
        state, pred, prevSorted4, pos4, nrm4, startArr, partials);

    reduce_kernel<<<dim3(1), 1024, 0, stream>>>(partials, out);
}

// Round 5
// 56.818 us; speedup vs baseline: 6.0563x; 1.1446x over previous
//
#include <hip/hip_runtime.h>
#include <limits.h>

#define NB      2
#define N_Q     20000
#define NBQ     (NB * N_Q)          // 40000
#define M_V     6890
#define N_F     13776
#define NBF     (NB * N_F)          // 27552
#define RAD2    0.01f               // 0.1^2
#define THRESH  0.001f
#define EPSN    1e-7f
#define SCALE   (1.0f / (float)(NB * N_Q))

// grid: 24^3, cell h=0.1 = radius, span [-1.2, 1.2] clamped.
// |dx| < r = h  =>  clamped cell coords differ by <= 1 per axis (clamp is a
// monotone 1-Lipschitz map applied identically to faces and queries).
#define GDIM    24
#define NCELLS  (GDIM * GDIM * GDIM)        // 13824
#define T_CELLS (NB * NCELLS)               // 27648
#define H_INV   10.0f
#define ORG     (-1.2f)

#define QPB     4                   // queries per block (1 per wave)
#define QBLOCKS (NBQ / QPB)         // 10000 exactly

#define SCAN_T  512
#define SCAN_K  (T_CELLS / SCAN_T)  // 54 exactly

__device__ __forceinline__ int cell_coord(float x) {
    int g = (int)floorf((x - ORG) * H_INV);
    return min(max(g, 0), GDIM - 1);
}

__device__ __forceinline__ int wave_min_i(int v) {
    #pragma unroll
    for (int m = 32; m; m >>= 1) v = min(v, __shfl_xor(v, m));
    return v;
}
__device__ __forceinline__ float wave_add_f(float v) {
    #pragma unroll
    for (int m = 32; m; m >>= 1) v += __shfl_xor(v, m);
    return v;
}

// ---------------- Kernel 1: per-face precompute + histogram ----------------
__global__ __launch_bounds__(256) void face_kernel(
    const float* __restrict__ h_state,   // [NB][M_V][9]
    const int*   __restrict__ h_faces,   // [NB][N_F][3]
    float4* __restrict__ prev4,
    float4* __restrict__ pos4,
    float4* __restrict__ nrm4,
    int* __restrict__ cellid,
    int* __restrict__ cellCnt)
{
    int t = blockIdx.x * 256 + threadIdx.x;
    if (t >= NBF) return;
    int b = t / N_F;
    const int* fc = h_faces + (size_t)t * 3;
    int i0 = fc[0], i1 = fc[1], i2 = fc[2];
    const float* hs = h_state + (size_t)b * M_V * 9;

    const float* v0 = hs + (size_t)i0 * 9;
    const float* v1 = hs + (size_t)i1 * 9;
    const float* v2 = hs + (size_t)i2 * 9;

    float ax = v0[0], ay = v0[1], az = v0[2];
    float bx = v1[0], by = v1[1], bz = v1[2];
    float cx = v2[0], cy = v2[1], cz = v2[2];

    float px = (ax + bx + cx) / 3.0f;
    float py = (ay + by + cy) / 3.0f;
    float pz = (az + bz + cz) / 3.0f;

    float e1x = bx - ax, e1y = by - ay, e1z = bz - az;
    float e2x = cx - ax, e2y = cy - ay, e2z = cz - az;
    float nx = e1y * e2z - e1z * e2y;
    float ny = e1z * e2x - e1x * e2z;
    float nz = e1x * e2y - e1y * e2x;
    float nrm = sqrtf(nx * nx + ny * ny + nz * nz);
    float den = fmaxf(nrm, EPSN);
    nx /= den; ny /= den; nz /= den;

    float qx = (v0[6] + v1[6] + v2[6]) / 3.0f;
    float qy = (v0[7] + v1[7] + v2[7]) / 3.0f;
    float qz = (v0[8] + v1[8] + v2[8]) / 3.0f;

    prev4[t] = make_float4(qx, qy, qz, 0.0f);
    pos4[t]  = make_float4(px, py, pz, 0.0f);
    nrm4[t]  = make_float4(nx, ny, nz, 0.0f);

    int gx = cell_coord(qx), gy = cell_coord(qy), gz = cell_coord(qz);
    int cid = b * NCELLS + (gz * GDIM + gy) * GDIM + gx;
    cellid[t] = cid;
    atomicAdd(&cellCnt[cid], 1);
}

// ---------------- Kernel 2: single-block exclusive scan over 27648 ---------
__global__ __launch_bounds__(SCAN_T) void scan_kernel(
    const int* __restrict__ cnt, int* __restrict__ start)
{
    __shared__ int sm[SCAN_T];
    int t = threadIdx.x;
    int base = t * SCAN_K;
    int v[SCAN_K];
    int s = 0;
    #pragma unroll
    for (int k = 0; k < SCAN_K; ++k) { v[k] = cnt[base + k]; s += v[k]; }
    sm[t] = s;
    __syncthreads();
    for (int off = 1; off < SCAN_T; off <<= 1) {
        int add = (t >= off) ? sm[t - off] : 0;
        __syncthreads();
        sm[t] += add;
        __syncthreads();
    }
    int pref = sm[t] - s;   // exclusive
    #pragma unroll
    for (int k = 0; k < SCAN_K; ++k) { start[base + k] = pref; pref += v[k]; }
    if (t == SCAN_T - 1) start[T_CELLS] = NBF;
}

// ---------------- Kernel 3: scatter faces; pack pos+id into 16B ------------
__global__ __launch_bounds__(256) void scatter_kernel(
    const int* __restrict__ cellid, int* __restrict__ cellCnt,
    const int* __restrict__ start, const float4* __restrict__ prev4,
    float4* __restrict__ prevSorted4)
{
    int t = blockIdx.x * 256 + threadIdx.x;
    if (t >= NBF) return;
    int c = cellid[t];
    int old = atomicSub(&cellCnt[c], 1);      // old in [1..cnt]
    float4 p = prev4[t];
    p.w = __int_as_float(t);                  // embed global face id
    prevSorted4[start[c] + old - 1] = p;
}

// ---------------- Kernel 4: one wave per query -----------------------------
#define CSW(a, b) { int _mn = min(a, b); int _mx = max(a, b); a = _mn; b = _mx; }

__global__ __launch_bounds__(256) void query_kernel(
    const float*  __restrict__ state,    // x_t0 queries
    const float*  __restrict__ pred,     // x_t1 for loss
    const float4* __restrict__ prevSorted4,
    const float4* __restrict__ pos4,
    const float4* __restrict__ nrm4,
    const int* __restrict__ start,
    float* __restrict__ partials)
{
    int tid  = threadIdx.x;
    int lane = tid & 63;
    int w    = tid >> 6;
    int q    = blockIdx.x * QPB + w;     // always < NBQ (exact grid)
    int b    = (q >= N_Q) ? 1 : 0;

    const float* st = state + (size_t)q * 3;
    float qx = st[0], qy = st[1], qz = st[2];
    const float* pr = pred + (size_t)q * 3;
    float x = pr[0], y = pr[1], z = pr[2];

    // preload the cnt==0 fallback face (face 0 of batch) -- static address
    float4 P0 = pos4[b * N_F];
    float4 N0 = nrm4[b * N_F];

    int cx = cell_coord(qx), cy = cell_coord(qy), cz = cell_coord(qz);

    // 9 neighbor rows (dz,dy), x-range fused into one contiguous span each
    int cum[10];
    int off[9];
    cum[0] = 0;
    int xlo = max(cx - 1, 0);
    int xhi = min(cx + 1, GDIM - 1);
    #pragma unroll
    for (int r = 0; r < 9; ++r) {
        int gz = cz + r / 3 - 1;
        int gy = cy + r % 3 - 1;
        int len = 0, j0 = 0;
        if (((unsigned)gz < (unsigned)GDIM) & ((unsigned)gy < (unsigned)GDIM)) {
            int cbase = b * NCELLS + (gz * GDIM + gy) * GDIM;
            j0  = start[cbase + xlo];
            len = start[cbase + xhi + 1] - j0;
        }
        off[r] = j0 - cum[r];
        cum[r + 1] = cum[r] + len;
    }
    int C = cum[9];

    // lanes split the candidate union
    int s0 = INT_MAX, s1 = INT_MAX, s2 = INT_MAX, s3 = INT_MAX;
    int s4 = INT_MAX, s5 = INT_MAX, s6 = INT_MAX, s7 = INT_MAX;
    int cnt = 0;
    float fsum = 0.0f;           // sum of f over this lane's hits
    int   lmin = INT_MAX;        // this lane's smallest hit id
    float fmin = 0.0f;           // its f

    int iters = (C + 63) >> 6;
    for (int it = 0; it < iters; ++it) {
        int k = (it << 6) + lane;
        int addr = off[0] + k;
        #pragma unroll
        for (int r = 1; r < 9; ++r)
            addr = (k >= cum[r]) ? off[r] + k : addr;
        if (k < C) {
            float4 p = prevSorted4[addr];
            float ddx = p.x - qx, ddy = p.y - qy, ddz = p.z - qz;
            float d2 = ddx * ddx + ddy * ddy + ddz * ddz;
            if (d2 < RAD2) {
                ++cnt;
                int tf = __float_as_int(p.w);
                // inline loss contribution for the fast path
                float4 P  = pos4[tf];
                float4 Nn = nrm4[tf];
                float d = (x - P.x) * Nn.x + (y - P.y) * Nn.y + (z - P.z) * Nn.z;
                float ip = fmaxf(THRESH - d, 0.0f);
                float f = ip * ip * ip;
                fsum += f;
                if (tf < lmin) { lmin = tf; fmin = f; }
                // keep 8 smallest for the (rare) slow path
                if (tf < s7) {
                    s7 = tf;
                    CSW(s6, s7); CSW(s5, s6); CSW(s4, s5); CSW(s3, s4);
                    CSW(s2, s3); CSW(s1, s2); CSW(s0, s1);
                }
            }
        }
    }

    // fused butterfly: (sum cnt, sum f, argmin pair) in one 6-step chain
    int   c_ = cnt;
    float fs = fsum;
    int   lm = lmin;
    float fm = fmin;
    #pragma unroll
    for (int m = 32; m; m >>= 1) {
        int   oc = __shfl_xor(c_, m);
        float os = __shfl_xor(fs, m);
        int   ol = __shfl_xor(lm, m);
        float of = __shfl_xor(fm, m);
        c_ += oc;
        fs += os;
        if (ol < lm) { lm = ol; fm = of; }
    }
    int cnt_tot = c_;            // wave-uniform

    float lsum;
    if (cnt_tot == 0) {
        float d0 = (x - P0.x) * N0.x + (y - P0.y) * N0.y + (z - P0.z) * N0.z;
        float ip0 = fmaxf(THRESH - d0, 0.0f);
        lsum = 8.0f * (ip0 * ip0 * ip0);
    } else if (cnt_tot <= 8) {
        // selected set == all hits; pad (8-cnt) copies of the min-id hit
        lsum = fs + (float)(8 - cnt_tot) * fm;
    } else {
        // slow path: extract the 8 smallest ids (unique across lanes)
        int t0, t1, t2, t3, t4, t5, t6, t7;
#define EXTRACT(TK)                                                      \
        {                                                                \
            int m = wave_min_i(s0);                                      \
            TK = m;                                                      \
            bool p = (s0 == m);                                          \
            s0 = p ? s1 : s0; s1 = p ? s2 : s1; s2 = p ? s3 : s2;        \
            s3 = p ? s4 : s3; s4 = p ? s5 : s4; s5 = p ? s6 : s5;        \
            s6 = p ? s7 : s6; s7 = p ? INT_MAX : s7;                     \
        }
        EXTRACT(t0) EXTRACT(t1) EXTRACT(t2) EXTRACT(t3)
        EXTRACT(t4) EXTRACT(t5) EXTRACT(t6) EXTRACT(t7)
#undef EXTRACT
        // lanes 0..7 compute the 8 contributions in parallel
        int v = t0;
        v = (lane == 1) ? t1 : v;
        v = (lane == 2) ? t2 : v;
        v = (lane == 3) ? t3 : v;
        v = (lane == 4) ? t4 : v;
        v = (lane == 5) ? t5 : v;
        v = (lane == 6) ? t6 : v;
        v = (lane == 7) ? t7 : v;
        float4 P  = pos4[v];
        float4 Nn = nrm4[v];
        float d = (x - P.x) * Nn.x + (y - P.y) * Nn.y + (z - P.z) * Nn.z;
        float ip = fmaxf(THRESH - d, 0.0f);
        float c = ip * ip * ip;
        c = (lane < 8) ? c : 0.0f;
        lsum = wave_add_f(c);
    }

    __shared__ float ws[QPB];
    if (lane == 0) ws[w] = lsum;
    __syncthreads();
    if (tid == 0)
        partials[blockIdx.x] = ws[0] + ws[1] + ws[2] + ws[3];
}

// ---------------- Kernel 5: final reduce -----------------------------------
__global__ __launch_bounds__(1024) void reduce_kernel(
    const float* __restrict__ partials, float* __restrict__ out)
{
    float s = 0.0f;
    for (int i = threadIdx.x; i < QBLOCKS; i += 1024)
        s += partials[i];
    s = wave_add_f(s);
    __shared__ float ws[16];
    int lane = threadIdx.x & 63, w = threadIdx.x >> 6;
    if (lane == 0) ws[w] = s;
    __syncthreads();
    if (threadIdx.x == 0) {
        float t = 0.0f;
        #pragma unroll
        for (int i = 0; i < 16; ++i) t += ws[i];
        out[0] = t * SCALE;
    }
}

extern "C" void kernel_launch(void* const* d_in, const int* in_sizes, int n_in,
                              void* d_out, int out_size, void* d_ws, size_t ws_size,
                              hipStream_t stream) {
    const float* pred    = (const float*)d_in[0];
    const float* state   = (const float*)d_in[1];
    const float* h_state = (const float*)d_in[2];
    const int*   h_faces = (const int*)d_in[3];
    float* out = (float*)d_out;

    // workspace layout (~2.2 MB)
    float4* prev4       = (float4*)d_ws;             // NBF
    float4* pos4        = prev4 + NBF;               // NBF
    float4* nrm4        = pos4 + NBF;                // NBF
    float4* prevSorted4 = nrm4 + NBF;                // NBF
    int* cellid         = (int*)(prevSorted4 + NBF); // NBF
    int* cellCnt        = cellid + NBF;              // T_CELLS
    int* startArr       = cellCnt + T_CELLS;         // T_CELLS + 1
    float* partials     = (float*)(startArr + T_CELLS + 1); // QBLOCKS

    hipMemsetAsync(cellCnt, 0, (size_t)T_CELLS * sizeof(int), stream);

    face_kernel<<<dim3((NBF + 255) / 256), 256, 0, stream>>>(
        h_state, h_faces, prev4, pos4, nrm4, cellid, cellCnt);

    scan_kernel<<<dim3(1), SCAN_T, 0, stream>>>(cellCnt, startArr);

    scatter_kernel<<<dim3((NBF + 255) / 256), 256, 0, stream>>>(
        cellid, cellCnt, startArr, prev4, prevSorted4);

    query_kernel<<<dim3(QBLOCKS), 256, 0, stream>>>(
        state, pred, prevSorted4, pos4, nrm4, startArr, partials);

    reduce_kernel<<<dim3(1), 1024, 0, stream>>>(partials, out);
}

// Round 6
// 48.665 us; speedup vs baseline: 7.0709x; 1.1675x over previous
//
#include <hip/hip_runtime.h>
#include <limits.h>

#define NB      2
#define N_Q     20000
#define NBQ     (NB * N_Q)          // 40000
#define M_V     6890
#define N_F     13776
#define NBF     (NB * N_F)          // 27552
#define RAD2    0.01f               // 0.1^2
#define THRESH  0.001f
#define EPSN    1e-7f
#define SCALE   (1.0f / (float)(NB * N_Q))

// grid: 12^3, cell h=0.2 = 2*radius, span [-1.2, 1.2] clamped.
// With h = 2r, the radius window spans at most 2 cells per axis: the home
// cell plus the neighbor on the side of the cell the query sits in.
// Clamp is monotone and applied identically to faces and queries; clamped
// neighbors that collapse onto the home cell are deduped via [lo,hi].
#define GDIM    12
#define NCELLS  (GDIM * GDIM * GDIM)        // 1728
#define T_CELLS (NB * NCELLS)               // 3456
#define H_INV   5.0f
#define ORG     (-1.2f)

#define QPB     8                   // queries per block (2 per wave)
#define QBLOCKS (NBQ / QPB)         // 5000 exactly

__device__ __forceinline__ int cell_coord(float x) {
    int g = (int)floorf((x - ORG) * H_INV);
    return min(max(g, 0), GDIM - 1);
}

// [lo,hi] cell window (1 or 2 cells) for a radius-r interval, h = 2r
__device__ __forceinline__ void axis_window(float v, int& lo, int& hi) {
    float s  = (v - ORG) * H_INV;
    float fl = floorf(s);
    int g_u  = (int)fl;
    int g    = min(max(g_u, 0), GDIM - 1);
    int sy   = ((s - fl) >= 0.5f) ? 1 : -1;
    int g2   = min(max(g_u + sy, 0), GDIM - 1);
    lo = min(g, g2);
    hi = max(g, g2);
}

__device__ __forceinline__ float wave_add_f(float v) {
    #pragma unroll
    for (int m = 32; m; m >>= 1) v += __shfl_xor(v, m);
    return v;
}

// ---------------- Kernel 1: per-face precompute + histogram ----------------
__global__ __launch_bounds__(256) void face_kernel(
    const float* __restrict__ h_state,   // [NB][M_V][9]
    const int*   __restrict__ h_faces,   // [NB][N_F][3]
    float4* __restrict__ prev4,
    float4* __restrict__ pos4,
    float4* __restrict__ nrm4,
    int* __restrict__ cellid,
    int* __restrict__ cellCnt)
{
    int t = blockIdx.x * 256 + threadIdx.x;
    if (t >= NBF) return;
    int b = t / N_F;
    const int* fc = h_faces + (size_t)t * 3;
    int i0 = fc[0], i1 = fc[1], i2 = fc[2];
    const float* hs = h_state + (size_t)b * M_V * 9;

    const float* v0 = hs + (size_t)i0 * 9;
    const float* v1 = hs + (size_t)i1 * 9;
    const float* v2 = hs + (size_t)i2 * 9;

    float ax = v0[0], ay = v0[1], az = v0[2];
    float bx = v1[0], by = v1[1], bz = v1[2];
    float cx = v2[0], cy = v2[1], cz = v2[2];

    float px = (ax + bx + cx) / 3.0f;
    float py = (ay + by + cy) / 3.0f;
    float pz = (az + bz + cz) / 3.0f;

    float e1x = bx - ax, e1y = by - ay, e1z = bz - az;
    float e2x = cx - ax, e2y = cy - ay, e2z = cz - az;
    float nx = e1y * e2z - e1z * e2y;
    float ny = e1z * e2x - e1x * e2z;
    float nz = e1x * e2y - e1y * e2x;
    float nrm = sqrtf(nx * nx + ny * ny + nz * nz);
    float den = fmaxf(nrm, EPSN);
    nx /= den; ny /= den; nz /= den;

    float qx = (v0[6] + v1[6] + v2[6]) / 3.0f;
    float qy = (v0[7] + v1[7] + v2[7]) / 3.0f;
    float qz = (v0[8] + v1[8] + v2[8]) / 3.0f;

    prev4[t] = make_float4(qx, qy, qz, 0.0f);
    pos4[t]  = make_float4(px, py, pz, 0.0f);
    nrm4[t]  = make_float4(nx, ny, nz, 0.0f);

    int gx = cell_coord(qx), gy = cell_coord(qy), gz = cell_coord(qz);
    int cid = b * NCELLS + (gz * GDIM + gy) * GDIM + gx;
    cellid[t] = cid;
    atomicAdd(&cellCnt[cid], 1);
}

// ---------------- Kernel 2: single-block exclusive scan over 3456 ----------
#define SCAN_K 14   // 256*14 = 3584 >= 3456
__global__ __launch_bounds__(256) void scan_kernel(
    const int* __restrict__ cnt, int* __restrict__ start)
{
    __shared__ int sm[256];
    int t = threadIdx.x;
    int base = t * SCAN_K;
    int v[SCAN_K];
    int s = 0;
    #pragma unroll
    for (int k = 0; k < SCAN_K; ++k) {
        int idx = base + k;
        v[k] = (idx < T_CELLS) ? cnt[idx] : 0;
        s += v[k];
    }
    sm[t] = s;
    __syncthreads();
    #pragma unroll
    for (int off = 1; off < 256; off <<= 1) {
        int add = (t >= off) ? sm[t - off] : 0;
        __syncthreads();
        sm[t] += add;
        __syncthreads();
    }
    int pref = sm[t] - s;   // exclusive
    #pragma unroll
    for (int k = 0; k < SCAN_K; ++k) {
        int idx = base + k;
        if (idx < T_CELLS) start[idx] = pref;
        pref += v[k];
    }
    if (t == 255) start[T_CELLS] = NBF;
}

// ---------------- Kernel 3: scatter faces; pack pos+id into 16B ------------
__global__ __launch_bounds__(256) void scatter_kernel(
    const int* __restrict__ cellid, int* __restrict__ cellCnt,
    const int* __restrict__ start, const float4* __restrict__ prev4,
    float4* __restrict__ prevSorted4)
{
    int t = blockIdx.x * 256 + threadIdx.x;
    if (t >= NBF) return;
    int c = cellid[t];
    int old = atomicSub(&cellCnt[c], 1);      // old in [1..cnt]
    float4 p = prev4[t];
    p.w = __int_as_float(t);                  // embed global face id
    prevSorted4[start[c] + old - 1] = p;
}

// ---------------- Kernel 4: half-wave (32 lanes) per query -----------------
#define CSW(a, b) { int _mn = min(a, b); int _mx = max(a, b); a = _mn; b = _mx; }

__device__ __forceinline__ int half_min_i(int v) {
    #pragma unroll
    for (int m = 16; m; m >>= 1) v = min(v, __shfl_xor(v, m));
    return v;
}

__global__ __launch_bounds__(256) void query_kernel(
    const float*  __restrict__ state,    // x_t0 queries
    const float*  __restrict__ pred,     // x_t1 for loss
    const float4* __restrict__ prevSorted4,
    const float4* __restrict__ pos4,
    const float4* __restrict__ nrm4,
    const int* __restrict__ start,
    float* __restrict__ partials)
{
    int tid  = threadIdx.x;
    int l32  = tid & 31;
    int hw   = tid >> 5;                 // half-wave id 0..7
    int q    = blockIdx.x * QPB + hw;    // always < NBQ (exact grid)
    int b    = (q >= N_Q) ? 1 : 0;       // uniform per block (20000 % 8 == 0)

    const float* st = state + (size_t)q * 3;
    float qx = st[0], qy = st[1], qz = st[2];
    const float* pr = pred + (size_t)q * 3;
    float x = pr[0], y = pr[1], z = pr[2];

    // preload the cnt==0 fallback face (face 0 of batch) -- static address
    float4 P0 = pos4[b * N_F];
    float4 N0 = nrm4[b * N_F];

    int xlo, xhi, ylo, yhi, zlo, zhi;
    axis_window(qx, xlo, xhi);
    axis_window(qy, ylo, yhi);
    axis_window(qz, zlo, zhi);

    // up to 4 rows (z,y), x-range fused into one contiguous span each
    int cum1, cum2, cum3, cum4;
    int off0, off1, off2, off3;
    {
        int c0 = 0;
        #define ROW(RR, CUMP, CUMN, OFFR)                                   \
        {                                                                   \
            int gz = zlo + ((RR) >> 1), gy = ylo + ((RR) & 1);              \
            int len = 0, j0 = 0;                                            \
            if (gz <= zhi && gy <= yhi) {                                   \
                int cbase = b * NCELLS + (gz * GDIM + gy) * GDIM;           \
                j0  = start[cbase + xlo];                                   \
                len = start[cbase + xhi + 1] - j0;                          \
            }                                                               \
            OFFR = j0 - CUMP;                                               \
            CUMN = CUMP + len;                                              \
        }
        ROW(0, c0,   cum1, off0)
        ROW(1, cum1, cum2, off1)
        ROW(2, cum2, cum3, off2)
        ROW(3, cum3, cum4, off3)
        #undef ROW
    }
    int C = cum4;

    // 32 lanes split this query's candidate union
    int s0 = INT_MAX, s1 = INT_MAX, s2 = INT_MAX, s3 = INT_MAX;
    int s4 = INT_MAX, s5 = INT_MAX, s6 = INT_MAX, s7 = INT_MAX;
    int cnt = 0;
    float fsum = 0.0f;
    int   lmin = INT_MAX;
    float fmin = 0.0f;

    int iters = (C + 31) >> 5;
    for (int it = 0; it < iters; ++it) {
        int k = (it << 5) + l32;
        int addr = off0 + k;
        addr = (k >= cum1) ? off1 + k : addr;
        addr = (k >= cum2) ? off2 + k : addr;
        addr = (k >= cum3) ? off3 + k : addr;
        if (k < C) {
            float4 p = prevSorted4[addr];
            float ddx = p.x - qx, ddy = p.y - qy, ddz = p.z - qz;
            float d2 = ddx * ddx + ddy * ddy + ddz * ddz;
            if (d2 < RAD2) {
                ++cnt;
                int tf = __float_as_int(p.w);
                float4 P  = pos4[tf];
                float4 Nn = nrm4[tf];
                float d = (x - P.x) * Nn.x + (y - P.y) * Nn.y + (z - P.z) * Nn.z;
                float ip = fmaxf(THRESH - d, 0.0f);
                float f = ip * ip * ip;
                fsum += f;
                if (tf < lmin) { lmin = tf; fmin = f; }
                if (tf < s7) {
                    s7 = tf;
                    CSW(s6, s7); CSW(s5, s6); CSW(s4, s5); CSW(s3, s4);
                    CSW(s2, s3); CSW(s1, s2); CSW(s0, s1);
                }
            }
        }
    }

    // fused 5-step butterfly within the half-wave:
    // (sum cnt, sum f, argmin pair) simultaneously
    int   c_ = cnt;
    float fs = fsum;
    int   lm = lmin;
    float fm = fmin;
    #pragma unroll
    for (int m = 16; m; m >>= 1) {
        int   oc = __shfl_xor(c_, m);
        float os = __shfl_xor(fs, m);
        int   ol = __shfl_xor(lm, m);
        float of = __shfl_xor(fm, m);
        c_ += oc;
        fs += os;
        if (ol < lm) { lm = ol; fm = of; }
    }
    int cnt_tot = c_;            // uniform within half-wave

    float lsum;
    if (cnt_tot == 0) {
        float d0 = (x - P0.x) * N0.x + (y - P0.y) * N0.y + (z - P0.z) * N0.z;
        float ip0 = fmaxf(THRESH - d0, 0.0f);
        lsum = 8.0f * (ip0 * ip0 * ip0);
    } else if (cnt_tot <= 8) {
        // selected set == all hits; pad (8-cnt) copies of the min-id hit
        lsum = fs + (float)(8 - cnt_tot) * fm;
    } else {
        // slow path: extract the 8 smallest ids (unique across lanes)
        int t0, t1, t2, t3, t4, t5, t6, t7;
#define EXTRACT(TK)                                                      \
        {                                                                \
            int m = half_min_i(s0);                                      \
            TK = m;                                                      \
            bool p = (s0 == m);                                          \
            s0 = p ? s1 : s0; s1 = p ? s2 : s1; s2 = p ? s3 : s2;        \
            s3 = p ? s4 : s3; s4 = p ? s5 : s4; s5 = p ? s6 : s5;        \
            s6 = p ? s7 : s6; s7 = p ? INT_MAX : s7;                     \
        }
        EXTRACT(t0) EXTRACT(t1) EXTRACT(t2) EXTRACT(t3)
        EXTRACT(t4) EXTRACT(t5) EXTRACT(t6) EXTRACT(t7)
#undef EXTRACT
        // lanes 0..7 of the half-wave compute the 8 contributions
        int v = t0;
        v = (l32 == 1) ? t1 : v;
        v = (l32 == 2) ? t2 : v;
        v = (l32 == 3) ? t3 : v;
        v = (l32 == 4) ? t4 : v;
        v = (l32 == 5) ? t5 : v;
        v = (l32 == 6) ? t6 : v;
        v = (l32 == 7) ? t7 : v;
        float4 P  = pos4[v];
        float4 Nn = nrm4[v];
        float d = (x - P.x) * Nn.x + (y - P.y) * Nn.y + (z - P.z) * Nn.z;
        float ip = fmaxf(THRESH - d, 0.0f);
        float c = ip * ip * ip;
        c = (l32 < 8) ? c : 0.0f;
        #pragma unroll
        for (int m = 16; m; m >>= 1) c += __shfl_xor(c, m);
        lsum = c;
    }

    __shared__ float ws[QPB];
    if (l32 == 0) ws[hw] = lsum;
    __syncthreads();
    if (tid == 0) {
        float s = 0.0f;
        #pragma unroll
        for (int k = 0; k < QPB; ++k) s += ws[k];
        partials[blockIdx.x] = s;
    }
}

// ---------------- Kernel 5: final reduce -----------------------------------
__global__ __launch_bounds__(1024) void reduce_kernel(
    const float* __restrict__ partials, float* __restrict__ out)
{
    float s = 0.0f;
    for (int i = threadIdx.x; i < QBLOCKS; i += 1024)
        s += partials[i];
    s = wave_add_f(s);
    __shared__ float ws[16];
    int lane = threadIdx.x & 63, w = threadIdx.x >> 6;
    if (lane == 0) ws[w] = s;
    __syncthreads();
    if (threadIdx.x == 0) {
        float t = 0.0f;
        #pragma unroll
        for (int i = 0; i < 16; ++i) t += ws[i];
        out[0] = t * SCALE;
    }
}

extern "C" void kernel_launch(void* const* d_in, const int* in_sizes, int n_in,
                              void* d_out, int out_size, void* d_ws, size_t ws_size,
                              hipStream_t stream) {
    const float* pred    = (const float*)d_in[0];
    const float* state   = (const float*)d_in[1];
    const float* h_state = (const float*)d_in[2];
    const int*   h_faces = (const int*)d_in[3];
    float* out = (float*)d_out;

    // workspace layout (~1.9 MB)
    float4* prev4       = (float4*)d_ws;             // NBF
    float4* pos4        = prev4 + NBF;               // NBF
    float4* nrm4        = pos4 + NBF;                // NBF
    float4* prevSorted4 = nrm4 + NBF;                // NBF
    int* cellid         = (int*)(prevSorted4 + NBF); // NBF
    int* cellCnt        = cellid + NBF;              // T_CELLS
    int* startArr       = cellCnt + T_CELLS;         // T_CELLS + 1
    float* partials     = (float*)(startArr + T_CELLS + 1); // QBLOCKS

    hipMemsetAsync(cellCnt, 0, (size_t)T_CELLS * sizeof(int), stream);

    face_kernel<<<dim3((NBF + 255) / 256), 256, 0, stream>>>(
        h_state, h_faces, prev4, pos4, nrm4, cellid, cellCnt);

    scan_kernel<<<dim3(1), 256, 0, stream>>>(cellCnt, startArr);

    scatter_kernel<<<dim3((NBF + 255) / 256), 256, 0, stream>>>(
        cellid, cellCnt, startArr, prev4, prevSorted4);

    query_kernel<<<dim3(QBLOCKS), 256, 0, stream>>>(
        state, pred, prevSorted4, pos4, nrm4, startArr, partials);

    reduce_kernel<<<dim3(1), 1024, 0, stream>>>(partials, out);
}